// Round 18
// baseline (398.913 us; speedup 1.0000x reference)
//
#include <hip/hip_runtime.h>
#include <hip/hip_bf16.h>

// GCN autoencoder: 4 layers sharing one COO adjacency (N=100000, E=3200000).
// Full associativity collapse: e2 = A(A(x@W12)), dec = (A(A(e2)))@(W3@W4).
// Round 18: (1) mm1 K-split — 4 waves = 2 row-tiles x 2 K-halves, LDS merge;
// doubles waves (6252, 6.1/SIMD) for the 205MB x-stream. (2) cv_loc split
// into rl_loc (1B row-local) + cv32_loc (4B packed col|val, final format):
// localsort writes 16MB not 25.6; refine pass1 reads 3.2MB not 25.6; pass2
// copies payload verbatim.
// INVARIANT: dec region holds only data whose last read precedes the first
// dec-writing kernel (spmm_dec). cv_csr/row_ptr live in d_ws.

#define N_NODES 100000
#define N_EDGES 3200000
#define RPB_LOG 7
#define RPB (1 << RPB_LOG)                       // 128 rows per bucket
#define NB ((N_NODES + RPB - 1) / RPB)           // 782 buckets
#define CHUNK 16384
#define NCHUNK ((N_EDGES + CHUNK - 1) / CHUNK)   // 196 chunks (tail 5120)
#define EPT (CHUNK / 512)                        // 32 edges per thread

typedef __attribute__((ext_vector_type(4))) float f32x4;
typedef __attribute__((ext_vector_type(8))) short s16x8;
typedef __attribute__((ext_vector_type(4))) unsigned short u16x4;
typedef __attribute__((ext_vector_type(4))) int i32x4;

// pack 8 fp32 -> 8 bf16 (RNE) in fragment element order e=0..7
static __device__ inline s16x8 cvt8(const float4& lo, const float4& hi) {
  unsigned p0, p1, p2, p3;
  asm("v_cvt_pk_bf16_f32 %0, %1, %2" : "=v"(p0) : "v"(lo.x), "v"(lo.y));
  asm("v_cvt_pk_bf16_f32 %0, %1, %2" : "=v"(p1) : "v"(lo.z), "v"(lo.w));
  asm("v_cvt_pk_bf16_f32 %0, %1, %2" : "=v"(p2) : "v"(hi.x), "v"(hi.y));
  asm("v_cvt_pk_bf16_f32 %0, %1, %2" : "=v"(p3) : "v"(hi.z), "v"(hi.w));
  i32x4 pi = {(int)p0, (int)p1, (int)p2, (int)p3};
  return __builtin_bit_cast(s16x8, pi);
}

static __device__ inline unsigned pk2(float a, float b) {  // 2 fp32 -> 2 bf16
  unsigned p;
  asm("v_cvt_pk_bf16_f32 %0, %1, %2" : "=v"(p) : "v"(a), "v"(b));
  return p;
}
static __device__ inline float b2f(unsigned short u) {
  return __uint_as_float(((unsigned)u) << 16);
}

// ---------------------------------------------------------------------------
// Wfrag12: B-fragments of W12 = W1@W2 (fp32 dot, one bf16 rounding).
// ---------------------------------------------------------------------------
__global__ __launch_bounds__(256) void wconv12_kernel(
    const float* __restrict__ W1, const float* __restrict__ W2,
    uint4* __restrict__ Wfrag) {
  int s = blockIdx.x * 256 + threadIdx.x;   // 1024 fragment-slots
  if (s >= 1024) return;
  int lane = s & 63, kt = s >> 6;
  int n = lane & 15;
  int kb = kt * 32 + (lane >> 4) * 8;
  unsigned p[4];
#pragma unroll
  for (int i = 0; i < 4; ++i) {
    float lo = 0.f, hi = 0.f;
#pragma unroll
    for (int m = 0; m < 32; ++m) {
      float w2 = W2[m * 16 + n];
      lo += W1[(kb + 2 * i) * 32 + m] * w2;
      hi += W1[(kb + 2 * i + 1) * 32 + m] * w2;
    }
    p[i] = pk2(lo, hi);
  }
  Wfrag[s] = make_uint4(p[0], p[1], p[2], p[3]);
}

// ---------------------------------------------------------------------------
// mm1: h[N,16](bf16) = x[N,512] @ W12[512,16] via mfma_f32_16x16x32_bf16.
// K-split: block = 64 rows, 4 waves = (row-tile 0/1) x (K-half 0/1); each
// wave does 8 kt steps of K=256; halves merged via LDS (one barrier).
// 1563 blocks -> 6252 waves (2x round-17) for the HBM x-stream.
// ---------------------------------------------------------------------------
__global__ __launch_bounds__(256) void mm1_kernel(
    const float* __restrict__ x, const uint4* __restrict__ Wfrag,
    unsigned short* __restrict__ out) {
  __shared__ float part[2][32][17];
  const int t = threadIdx.x;
  const int lane = t & 63;
  const int w = t >> 6;
  const int tile = w & 1;
  const int kh = w >> 1;
  const int rbase = blockIdx.x * 64 + tile * 32;
  const int lrow = lane & 15;
  const int kg = lane >> 4;

  int r0c = rbase + lrow;       if (r0c > N_NODES - 1) r0c = N_NODES - 1;
  int r1c = rbase + 16 + lrow;  if (r1c > N_NODES - 1) r1c = N_NODES - 1;
  const float* xp0 = x + (size_t)r0c * 512 + kh * 256 + kg * 8;
  const float* xp1 = x + (size_t)r1c * 512 + kh * 256 + kg * 8;
  const s16x8* Wf = (const s16x8*)Wfrag;

  f32x4 acc0 = {0.f, 0.f, 0.f, 0.f}, acc1 = {0.f, 0.f, 0.f, 0.f};

#pragma unroll 4
  for (int kt = 0; kt < 8; ++kt) {
    float4 a0lo = *(const float4*)(xp0 + kt * 32);
    float4 a0hi = *(const float4*)(xp0 + kt * 32 + 4);
    float4 a1lo = *(const float4*)(xp1 + kt * 32);
    float4 a1hi = *(const float4*)(xp1 + kt * 32 + 4);
    s16x8 b = Wf[(kh * 8 + kt) * 64 + lane];
    s16x8 a0 = cvt8(a0lo, a0hi);
    s16x8 a1 = cvt8(a1lo, a1hi);
    acc0 = __builtin_amdgcn_mfma_f32_16x16x32_bf16(a0, b, acc0, 0, 0, 0);
    acc1 = __builtin_amdgcn_mfma_f32_16x16x32_bf16(a1, b, acc1, 0, 0, 0);
  }

  const int col = lane & 15;
  if (kh == 1) {
#pragma unroll
    for (int reg = 0; reg < 4; ++reg) {
      part[tile][kg * 4 + reg][col] = acc0[reg];
      part[tile][16 + kg * 4 + reg][col] = acc1[reg];
    }
  }
  __syncthreads();
  if (kh == 0) {
#pragma unroll
    for (int reg = 0; reg < 4; ++reg) {
      int l0 = kg * 4 + reg;
      int r0 = rbase + l0;
      if (r0 < N_NODES) {
        float v = acc0[reg] + part[tile][l0][col];
        out[(size_t)r0 * 16 + col] = (unsigned short)(pk2(v, v) & 0xFFFF);
      }
      int l1 = 16 + kg * 4 + reg;
      int r1 = rbase + l1;
      if (r1 < N_NODES) {
        float v = acc1[reg] + part[tile][l1][col];
        out[(size_t)r1 * 16 + col] = (unsigned short)(pk2(v, v) & 0xFFFF);
      }
    }
  }
}

// ---------------------------------------------------------------------------
// Phase A: per-chunk counting sort by bucket into the chunk's OWN slot.
// Writes SPLIT payload: rl_loc (1B row-local) + cv32_loc (4B packed
// (col<<15)|bf16(val) — the FINAL cv_csr format). Bucket totals -> gcnt.
// ---------------------------------------------------------------------------
__global__ __launch_bounds__(512) void localsort_kernel(
    const int* __restrict__ rows, const int* __restrict__ cols,
    const float* __restrict__ vals, unsigned char* __restrict__ rl_loc,
    unsigned* __restrict__ cv32_loc, int* __restrict__ ofs,
    int* __restrict__ gcnt) {
  __shared__ int lcnt[NB];
  __shared__ int lofs[NB + 1];
  __shared__ int ssum[512];
  const int c = blockIdx.x, t = threadIdx.x;
  const int c0 = c * CHUNK, c1 = min(c0 + CHUNK, N_EDGES);

  for (int i = t; i < NB; i += 512) lcnt[i] = 0;
  __syncthreads();

  int rr[EPT];
#pragma unroll
  for (int u = 0; u < EPT; ++u) {
    int e = c0 + t + u * 512;
    rr[u] = (e < c1) ? rows[e] : -1;
    if (rr[u] >= 0) atomicAdd(&lcnt[rr[u] >> RPB_LOG], 1);
  }
  __syncthreads();

  int v0 = (2 * t < NB) ? lcnt[2 * t] : 0;
  int v1 = (2 * t + 1 < NB) ? lcnt[2 * t + 1] : 0;
  if (v0) atomicAdd(&gcnt[2 * t], v0);
  if (v1) atomicAdd(&gcnt[2 * t + 1], v1);
  ssum[t] = v0 + v1;
  __syncthreads();
  for (int off = 1; off < 512; off <<= 1) {
    int xv = (t >= off) ? ssum[t - off] : 0;
    __syncthreads();
    ssum[t] += xv;
    __syncthreads();
  }
  int excl = (t == 0) ? 0 : ssum[t - 1];
  if (2 * t < NB) lofs[2 * t] = excl;
  if (2 * t + 1 < NB) lofs[2 * t + 1] = excl + v0;
  if (t == 511) lofs[NB] = ssum[511];
  __syncthreads();

  for (int i = t; i <= NB; i += 512) ofs[c * (NB + 1) + i] = lofs[i];
  for (int i = t; i < NB; i += 512) lcnt[i] = 0;   // reuse as cursor
  __syncthreads();

#pragma unroll
  for (int u = 0; u < EPT; ++u) {
    int r = rr[u];
    if (r >= 0) {
      int e = c0 + t + u * 512;
      int b = r >> RPB_LOG;
      int rank = atomicAdd(&lcnt[b], 1);
      int pos = c0 + lofs[b] + rank;
      float v = vals[e];
      rl_loc[pos] = (unsigned char)(r & (RPB - 1));
      cv32_loc[pos] = ((unsigned)cols[e] << 15) | (pk2(v, v) & 0x7FFF);
    }
  }
}

// ---------------------------------------------------------------------------
// Phase B: per-bucket counting sort -> cv_csr + row_ptr.
// bstart computed in-block (reduce of gcnt[0..b-1]). Pass 1 reads ONLY the
// 1B rl array; pass 2 copies the 4B payload verbatim. Coalesced strided
// loop + incremental monotone group cursor.
// ---------------------------------------------------------------------------
__global__ __launch_bounds__(256) void refine6_kernel(
    const int* __restrict__ ofs, const int* __restrict__ gcnt,
    const unsigned char* __restrict__ rl_loc,
    const unsigned* __restrict__ cv32_loc, unsigned* __restrict__ cv_csr,
    int* __restrict__ row_ptr) {
  __shared__ int gs[NCHUNK];       // group global start (edge index)
  __shared__ int q[NCHUNK + 1];    // within-bucket exclusive offsets
  __shared__ int sq[256];
  __shared__ int rcnt[RPB];
  __shared__ int rbase[RPB];
  __shared__ int bstart_s;
  const int b = blockIdx.x, t = threadIdx.x;

  // ---- bstart_b = sum_{i<b} gcnt[i] (block reduce) ----
  int part = 0;
  for (int i = t; i < b; i += 256) part += gcnt[i];
  sq[t] = part;
  __syncthreads();
  for (int off = 128; off > 0; off >>= 1) {
    if (t < off) sq[t] += sq[t + off];
    __syncthreads();
  }
  if (t == 0) bstart_s = sq[0];
  __syncthreads();

  // ---- group table + within-bucket offsets ----
  int cnt_t = 0;
  if (t < NCHUNK) {
    int g0 = ofs[t * (NB + 1) + b];
    int g1 = ofs[t * (NB + 1) + b + 1];
    gs[t] = t * CHUNK + g0;
    cnt_t = g1 - g0;
  }
  sq[t] = cnt_t;
  __syncthreads();
  for (int off = 1; off < 256; off <<= 1) {
    int v = (t >= off) ? sq[t - off] : 0;
    __syncthreads();
    sq[t] += v;
    __syncthreads();
  }
  if (t < NCHUNK) q[t] = sq[t] - cnt_t;
  if (t == 0) q[NCHUNK] = sq[255];
  if (t < RPB) rcnt[t] = 0;
  __syncthreads();
  const int Q = q[NCHUNK];

  // pass 1: row histogram from 1B rl array (monotone group cursor)
  int lo = 0;
  for (int i = t; i < Q; i += 256) {
    while (q[lo + 1] <= i) ++lo;
    atomicAdd(&rcnt[rl_loc[gs[lo] + (i - q[lo])]], 1);
  }
  __syncthreads();

  int rv = (t < RPB) ? rcnt[t] : 0;
  sq[t] = rv;
  __syncthreads();
  for (int off = 1; off < RPB; off <<= 1) {
    int v = (t >= off && t < RPB) ? sq[t - off] : 0;
    __syncthreads();
    if (t < RPB) sq[t] += v;
    __syncthreads();
  }
  if (t < RPB) {
    int base = bstart_s + sq[t] - rv;
    rbase[t] = base;
    int gr = (b << RPB_LOG) + t;
    if (gr < N_NODES) row_ptr[gr] = base;
    rcnt[t] = 0;                               // reuse as cursor
  }
  if (b == 0 && t == 0) row_ptr[N_NODES] = N_EDGES;
  __syncthreads();

  // pass 2: rank-scatter; payload copied verbatim (already final format)
  lo = 0;
  for (int i = t; i < Q; i += 256) {
    while (q[lo + 1] <= i) ++lo;
    int idx = gs[lo] + (i - q[lo]);
    int rl = rl_loc[idx];
    int rank = atomicAdd(&rcnt[rl], 1);
    cv_csr[rbase[rl] + rank] = cv32_loc[idx];
  }
}

// ---------------------------------------------------------------------------
// CSR SpMM, bf16 gather table (3.2MB, L2-hot), 4B packed edges.
// 8 threads/row = 4 col-lanes x 2 edge-halves; halves combined via
// __shfl_xor(.,4). 32 rows/block -> 3125 blocks. OM: 0 bf16; 1 bf16+fp32.
// ---------------------------------------------------------------------------
template <int OM>
__global__ __launch_bounds__(256) void spmm_b16_kernel(
    const int* __restrict__ rp, const unsigned* __restrict__ colval,
    const unsigned short* __restrict__ in, unsigned short* __restrict__ outb,
    float* __restrict__ outf) {
  const int t = threadIdx.x;
  const int r = blockIdx.x * 32 + (t >> 3);   // 3125*32 == N exactly
  const int q = t & 3;
  const int hh = (t >> 2) & 1;
  const int k0 = rp[r], k1 = rp[r + 1];
  const int len0 = (k1 - k0 + 1) >> 1;
  int k = k0 + hh * len0;
  const int ke = hh ? k1 : (k0 + len0);
  float a0 = 0.f, a1 = 0.f, a2 = 0.f, a3 = 0.f;

  for (; k + 7 < ke; k += 8) {            // 8 independent gathers in flight
    unsigned cv[8];
#pragma unroll
    for (int u = 0; u < 8; ++u) cv[u] = colval[k + u];
    u16x4 g[8];
#pragma unroll
    for (int u = 0; u < 8; ++u)
      g[u] = *(const u16x4*)(in + (size_t)(cv[u] >> 15) * 16 + q * 4);
#pragma unroll
    for (int u = 0; u < 8; ++u) {
      float v = __uint_as_float((cv[u] & 0x7FFF) << 16);
      a0 += v * b2f(g[u][0]);
      a1 += v * b2f(g[u][1]);
      a2 += v * b2f(g[u][2]);
      a3 += v * b2f(g[u][3]);
    }
  }
  for (; k + 3 < ke; k += 4) {            // 4-deep tail
    unsigned cv[4];
#pragma unroll
    for (int u = 0; u < 4; ++u) cv[u] = colval[k + u];
    u16x4 g[4];
#pragma unroll
    for (int u = 0; u < 4; ++u)
      g[u] = *(const u16x4*)(in + (size_t)(cv[u] >> 15) * 16 + q * 4);
#pragma unroll
    for (int u = 0; u < 4; ++u) {
      float v = __uint_as_float((cv[u] & 0x7FFF) << 16);
      a0 += v * b2f(g[u][0]);
      a1 += v * b2f(g[u][1]);
      a2 += v * b2f(g[u][2]);
      a3 += v * b2f(g[u][3]);
    }
  }
  for (; k < ke; ++k) {
    unsigned cv = colval[k];
    u16x4 g = *(const u16x4*)(in + (size_t)(cv >> 15) * 16 + q * 4);
    float v = __uint_as_float((cv & 0x7FFF) << 16);
    a0 += v * b2f(g[0]); a1 += v * b2f(g[1]);
    a2 += v * b2f(g[2]); a3 += v * b2f(g[3]);
  }

  a0 += __shfl_xor(a0, 4);
  a1 += __shfl_xor(a1, 4);
  a2 += __shfl_xor(a2, 4);
  a3 += __shfl_xor(a3, 4);

  if (hh == 0) {
    uint2 pk = make_uint2(pk2(a0, a1), pk2(a2, a3));
    *(uint2*)(outb + (size_t)r * 16 + q * 4) = pk;
    if (OM == 1)
      *(float4*)(outf + (size_t)r * 16 + q * 4) = make_float4(a0, a1, a2, a3);
  }
}

// ---------------------------------------------------------------------------
// spmm_dec: fused  t3 = A @ t2  (split gather + shfl combine -> LDS tile),
// then dec = t3 @ (W3@W4) (W34 cols built incrementally in regs, coalesced
// writes). Block = 32 rows. Reads d_ws scratch ONLY; writes dec ONLY.
// ---------------------------------------------------------------------------
__global__ __launch_bounds__(256) void spmm_dec_kernel(
    const int* __restrict__ rp, const unsigned* __restrict__ colval,
    const unsigned short* __restrict__ in, const float* __restrict__ W3,
    const float* __restrict__ W4, float* __restrict__ out) {
  __shared__ float t3s[32][20];
  const int t = threadIdx.x;
  const int r0 = blockIdx.x * 32;
  const int lr = t >> 3;
  const int q = t & 3;
  const int hh = (t >> 2) & 1;
  const int r = r0 + lr;

  // ---- W34 columns t, t+256 built incrementally ----
  float wa[16], wb[16];
#pragma unroll
  for (int kk = 0; kk < 16; ++kk) { wa[kk] = 0.f; wb[kk] = 0.f; }
#pragma unroll
  for (int m = 0; m < 32; ++m) {
    float w4A = W4[m * 512 + t];
    float w4B = W4[m * 512 + t + 256];
#pragma unroll
    for (int kk = 0; kk < 16; ++kk) {
      float w3 = W3[kk * 32 + m];         // uniform -> s_load
      wa[kk] += w3 * w4A;
      wb[kk] += w3 * w4B;
    }
  }

  // ---- split gather phase ----
  const int k0 = rp[r], k1 = rp[r + 1];
  const int len0 = (k1 - k0 + 1) >> 1;
  int k = k0 + hh * len0;
  const int ke = hh ? k1 : (k0 + len0);
  float a0 = 0.f, a1 = 0.f, a2 = 0.f, a3 = 0.f;
  for (; k + 7 < ke; k += 8) {
    unsigned cv[8];
#pragma unroll
    for (int u = 0; u < 8; ++u) cv[u] = colval[k + u];
    u16x4 g[8];
#pragma unroll
    for (int u = 0; u < 8; ++u)
      g[u] = *(const u16x4*)(in + (size_t)(cv[u] >> 15) * 16 + q * 4);
#pragma unroll
    for (int u = 0; u < 8; ++u) {
      float v = __uint_as_float((cv[u] & 0x7FFF) << 16);
      a0 += v * b2f(g[u][0]);
      a1 += v * b2f(g[u][1]);
      a2 += v * b2f(g[u][2]);
      a3 += v * b2f(g[u][3]);
    }
  }
  for (; k + 3 < ke; k += 4) {
    unsigned cv[4];
#pragma unroll
    for (int u = 0; u < 4; ++u) cv[u] = colval[k + u];
    u16x4 g[4];
#pragma unroll
    for (int u = 0; u < 4; ++u)
      g[u] = *(const u16x4*)(in + (size_t)(cv[u] >> 15) * 16 + q * 4);
#pragma unroll
    for (int u = 0; u < 4; ++u) {
      float v = __uint_as_float((cv[u] & 0x7FFF) << 16);
      a0 += v * b2f(g[u][0]);
      a1 += v * b2f(g[u][1]);
      a2 += v * b2f(g[u][2]);
      a3 += v * b2f(g[u][3]);
    }
  }
  for (; k < ke; ++k) {
    unsigned cv = colval[k];
    u16x4 g = *(const u16x4*)(in + (size_t)(cv >> 15) * 16 + q * 4);
    float v = __uint_as_float((cv & 0x7FFF) << 16);
    a0 += v * b2f(g[0]); a1 += v * b2f(g[1]);
    a2 += v * b2f(g[2]); a3 += v * b2f(g[3]);
  }
  a0 += __shfl_xor(a0, 4);
  a1 += __shfl_xor(a1, 4);
  a2 += __shfl_xor(a2, 4);
  a3 += __shfl_xor(a3, 4);
  if (hh == 0) {
    t3s[lr][q * 4 + 0] = a0;
    t3s[lr][q * 4 + 1] = a1;
    t3s[lr][q * 4 + 2] = a2;
    t3s[lr][q * 4 + 3] = a3;
  }
  __syncthreads();

  // ---- dec rows: per local row, 2 coalesced column writes/thread ----
  for (int rr = 0; rr < 32; ++rr) {
    float4 c0 = *(const float4*)&t3s[rr][0];    // uniform -> broadcast
    float4 c1 = *(const float4*)&t3s[rr][4];
    float4 c2 = *(const float4*)&t3s[rr][8];
    float4 c3 = *(const float4*)&t3s[rr][12];
    float sa = c0.x * wa[0] + c0.y * wa[1] + c0.z * wa[2] + c0.w * wa[3]
             + c1.x * wa[4] + c1.y * wa[5] + c1.z * wa[6] + c1.w * wa[7]
             + c2.x * wa[8] + c2.y * wa[9] + c2.z * wa[10] + c2.w * wa[11]
             + c3.x * wa[12] + c3.y * wa[13] + c3.z * wa[14] + c3.w * wa[15];
    float sb = c0.x * wb[0] + c0.y * wb[1] + c0.z * wb[2] + c0.w * wb[3]
             + c1.x * wb[4] + c1.y * wb[5] + c1.z * wb[6] + c1.w * wb[7]
             + c2.x * wb[8] + c2.y * wb[9] + c2.z * wb[10] + c2.w * wb[11]
             + c3.x * wb[12] + c3.y * wb[13] + c3.z * wb[14] + c3.w * wb[15];
    float* o = out + (size_t)(r0 + rr) * 512;
    o[t] = sa;
    o[t + 256] = sb;
  }
}

// ---------------------------------------------------------------------------
extern "C" void kernel_launch(void* const* d_in, const int* in_sizes, int n_in,
                              void* d_out, int out_size, void* d_ws, size_t ws_size,
                              hipStream_t stream) {
  const float* x     = (const float*)d_in[0];
  const int*   arows = (const int*)d_in[1];
  const int*   acols = (const int*)d_in[2];
  const float* avals = (const float*)d_in[3];
  const float* W1    = (const float*)d_in[4];  // [512,32]
  const float* W2    = (const float*)d_in[5];  // [32,16]
  const float* W3    = (const float*)d_in[6];  // [16,32]
  const float* W4    = (const float*)d_in[7];  // [32,512]

  float* out = (float*)d_out;
  float* dec = out;                            // [N,512] written LAST
  float* enc = out + (size_t)N_NODES * 512;    // [N,16]

  // d_ws (22.8MB <= proven 25.6MB): 3 bf16 [N,16] ping-pong buffers +
  // everything the FINAL kernel reads (cv_csr, row_ptr).
  unsigned short* bh  = (unsigned short*)d_ws;      // h; reused for t2
  unsigned short* bu  = bh + (size_t)N_NODES * 16;  // u1
  unsigned short* be  = bu + (size_t)N_NODES * 16;  // e2 bf16 copy
  unsigned* cv_csr  = (unsigned*)(be + (size_t)N_NODES * 16);  // [E] 4B packed
  int*      row_ptr = (int*)(cv_csr + N_EDGES);     // [N+1]

  // dec-region scratch — all reads complete BEFORE spmm_dec launches.
  unsigned char* rl_loc   = (unsigned char*)dec;    // [E] 1B row-local
  unsigned*      cv32_loc = (unsigned*)(rl_loc + ((N_EDGES + 15) & ~15)); // [E] 4B
  uint4*         Wfrag    = (uint4*)(cv32_loc + N_EDGES);  // [1024]
  int*           ofs      = (int*)(Wfrag + 1024);          // [NCHUNK][NB+1]
  int*           gcnt     = ofs + NCHUNK * (NB + 1);       // [NB]

  // ---- build CSR + pack W12 = W1@W2 fragments ----
  hipMemsetAsync(gcnt, 0, NB * sizeof(int), stream);
  wconv12_kernel<<<4, 256, 0, stream>>>(W1, W2, Wfrag);
  localsort_kernel<<<NCHUNK, 512, 0, stream>>>(arows, acols, avals, rl_loc,
                                               cv32_loc, ofs, gcnt);
  refine6_kernel<<<NB, 256, 0, stream>>>(ofs, gcnt, rl_loc, cv32_loc,
                                         cv_csr, row_ptr);

  // ---- pipeline (all spmms D=16, bf16 tables, 4B edges) ----
  const int spGrid = N_NODES / 32;  // 3125, exact
  mm1_kernel<<<(N_NODES + 63) / 64, 256, 0, stream>>>(x, Wfrag, bh);         // h  -> bh
  spmm_b16_kernel<0><<<spGrid, 256, 0, stream>>>(row_ptr, cv_csr, bh, bu, nullptr);   // u1 -> bu
  spmm_b16_kernel<1><<<spGrid, 256, 0, stream>>>(row_ptr, cv_csr, bu, be, enc);       // e2 -> be (+enc)
  spmm_b16_kernel<0><<<spGrid, 256, 0, stream>>>(row_ptr, cv_csr, be, bh, nullptr);   // t2 -> bh (reuse)
  spmm_dec_kernel<<<spGrid, 256, 0, stream>>>(row_ptr, cv_csr, bh, W3, W4, dec);      // t3+dec
}

// Round 19
// 358.286 us; speedup vs baseline: 1.1134x; 1.1134x over previous
//
#include <hip/hip_runtime.h>
#include <hip/hip_bf16.h>

// GCN autoencoder: 4 layers sharing one COO adjacency (N=100000, E=3200000).
// Full associativity collapse: e2 = A(A(x@W12)), dec = (A(A(e2)))@(W3@W4).
// Round 19: REVERT to round-17 config (365us, best). Round 18's two edits
// both regressed: mm1 K-split (LDS merge + barrier > wave-count gain) and
// rl/cv32 split (1-byte scatter -> partial-sector RMW). One cleanup kept:
// gcnt zeroing folded into wconv12 (deletes the memset launch).
// INVARIANT: dec region holds only data whose last read precedes the first
// dec-writing kernel (spmm_dec). cv_csr/row_ptr live in d_ws.

#define N_NODES 100000
#define N_EDGES 3200000
#define RPB_LOG 7
#define RPB (1 << RPB_LOG)                       // 128 rows per bucket
#define NB ((N_NODES + RPB - 1) / RPB)           // 782 buckets
#define CHUNK 16384
#define NCHUNK ((N_EDGES + CHUNK - 1) / CHUNK)   // 196 chunks (tail 5120)
#define EPT (CHUNK / 512)                        // 32 edges per thread

typedef __attribute__((ext_vector_type(4))) float f32x4;
typedef __attribute__((ext_vector_type(8))) short s16x8;
typedef __attribute__((ext_vector_type(4))) unsigned short u16x4;
typedef __attribute__((ext_vector_type(4))) int i32x4;

// pack 8 fp32 -> 8 bf16 (RNE) in fragment element order e=0..7
static __device__ inline s16x8 cvt8(const float4& lo, const float4& hi) {
  unsigned p0, p1, p2, p3;
  asm("v_cvt_pk_bf16_f32 %0, %1, %2" : "=v"(p0) : "v"(lo.x), "v"(lo.y));
  asm("v_cvt_pk_bf16_f32 %0, %1, %2" : "=v"(p1) : "v"(lo.z), "v"(lo.w));
  asm("v_cvt_pk_bf16_f32 %0, %1, %2" : "=v"(p2) : "v"(hi.x), "v"(hi.y));
  asm("v_cvt_pk_bf16_f32 %0, %1, %2" : "=v"(p3) : "v"(hi.z), "v"(hi.w));
  i32x4 pi = {(int)p0, (int)p1, (int)p2, (int)p3};
  return __builtin_bit_cast(s16x8, pi);
}

static __device__ inline unsigned pk2(float a, float b) {  // 2 fp32 -> 2 bf16
  unsigned p;
  asm("v_cvt_pk_bf16_f32 %0, %1, %2" : "=v"(p) : "v"(a), "v"(b));
  return p;
}
static __device__ inline float b2f(unsigned short u) {
  return __uint_as_float(((unsigned)u) << 16);
}

// ---------------------------------------------------------------------------
// Wfrag12: B-fragments of W12 = W1@W2 (fp32 dot, one bf16 rounding).
// Also zeroes gcnt (1024 threads >= NB) — replaces the memset launch.
// ---------------------------------------------------------------------------
__global__ __launch_bounds__(256) void wconv12_kernel(
    const float* __restrict__ W1, const float* __restrict__ W2,
    uint4* __restrict__ Wfrag, int* __restrict__ gcnt) {
  int s = blockIdx.x * 256 + threadIdx.x;   // 1024 fragment-slots
  if (s < NB) gcnt[s] = 0;
  if (s >= 1024) return;
  int lane = s & 63, kt = s >> 6;
  int n = lane & 15;
  int kb = kt * 32 + (lane >> 4) * 8;
  unsigned p[4];
#pragma unroll
  for (int i = 0; i < 4; ++i) {
    float lo = 0.f, hi = 0.f;
#pragma unroll
    for (int m = 0; m < 32; ++m) {
      float w2 = W2[m * 16 + n];
      lo += W1[(kb + 2 * i) * 32 + m] * w2;
      hi += W1[(kb + 2 * i + 1) * 32 + m] * w2;
    }
    p[i] = pk2(lo, hi);
  }
  Wfrag[s] = make_uint4(p[0], p[1], p[2], p[3]);
}

// ---------------------------------------------------------------------------
// mm1: h[N,16](bf16) = x[N,512] @ W12[512,16] via mfma_f32_16x16x32_bf16.
// (round-17 form: 128 rows/block, no K-split — K-split regressed in r18)
// ---------------------------------------------------------------------------
__global__ __launch_bounds__(256) void mm1_kernel(
    const float* __restrict__ x, const uint4* __restrict__ Wfrag,
    unsigned short* __restrict__ out) {
  const int t = threadIdx.x;
  const int lane = t & 63;
  const int w = t >> 6;
  const int rbase = blockIdx.x * 128 + w * 32;
  const int lrow = lane & 15;
  const int kg = lane >> 4;

  int r0c = rbase + lrow;       if (r0c > N_NODES - 1) r0c = N_NODES - 1;
  int r1c = rbase + 16 + lrow;  if (r1c > N_NODES - 1) r1c = N_NODES - 1;
  const float* xp0 = x + (size_t)r0c * 512 + kg * 8;
  const float* xp1 = x + (size_t)r1c * 512 + kg * 8;
  const s16x8* Wf = (const s16x8*)Wfrag;

  f32x4 acc0 = {0.f, 0.f, 0.f, 0.f}, acc1 = {0.f, 0.f, 0.f, 0.f};

#pragma unroll 4
  for (int kt = 0; kt < 16; ++kt) {
    float4 a0lo = *(const float4*)(xp0 + kt * 32);
    float4 a0hi = *(const float4*)(xp0 + kt * 32 + 4);
    float4 a1lo = *(const float4*)(xp1 + kt * 32);
    float4 a1hi = *(const float4*)(xp1 + kt * 32 + 4);
    s16x8 b = Wf[kt * 64 + lane];
    s16x8 a0 = cvt8(a0lo, a0hi);
    s16x8 a1 = cvt8(a1lo, a1hi);
    acc0 = __builtin_amdgcn_mfma_f32_16x16x32_bf16(a0, b, acc0, 0, 0, 0);
    acc1 = __builtin_amdgcn_mfma_f32_16x16x32_bf16(a1, b, acc1, 0, 0, 0);
  }

  const int col = lane & 15;
#pragma unroll
  for (int reg = 0; reg < 4; ++reg) {
    int r0 = rbase + kg * 4 + reg;
    if (r0 < N_NODES)
      out[(size_t)r0 * 16 + col] = (unsigned short)(pk2(acc0[reg], acc0[reg]) & 0xFFFF);
    int r1 = rbase + 16 + kg * 4 + reg;
    if (r1 < N_NODES)
      out[(size_t)r1 * 16 + col] = (unsigned short)(pk2(acc1[reg], acc1[reg]) & 0xFFFF);
  }
}

// ---------------------------------------------------------------------------
// Phase A: per-chunk counting sort by bucket into the chunk's OWN slot.
// Bucket totals folded in via atomicAdd(gcnt). 8B int2 payload (round-17).
// ---------------------------------------------------------------------------
__global__ __launch_bounds__(512) void localsort_kernel(
    const int* __restrict__ rows, const int* __restrict__ cols,
    const float* __restrict__ vals, int2* __restrict__ cv_loc,
    int* __restrict__ ofs, int* __restrict__ gcnt) {
  __shared__ int lcnt[NB];
  __shared__ int lofs[NB + 1];
  __shared__ int ssum[512];
  const int c = blockIdx.x, t = threadIdx.x;
  const int c0 = c * CHUNK, c1 = min(c0 + CHUNK, N_EDGES);

  for (int i = t; i < NB; i += 512) lcnt[i] = 0;
  __syncthreads();

  int rr[EPT];
#pragma unroll
  for (int u = 0; u < EPT; ++u) {
    int e = c0 + t + u * 512;
    rr[u] = (e < c1) ? rows[e] : -1;
    if (rr[u] >= 0) atomicAdd(&lcnt[rr[u] >> RPB_LOG], 1);
  }
  __syncthreads();

  int v0 = (2 * t < NB) ? lcnt[2 * t] : 0;
  int v1 = (2 * t + 1 < NB) ? lcnt[2 * t + 1] : 0;
  if (v0) atomicAdd(&gcnt[2 * t], v0);
  if (v1) atomicAdd(&gcnt[2 * t + 1], v1);
  ssum[t] = v0 + v1;
  __syncthreads();
  for (int off = 1; off < 512; off <<= 1) {
    int xv = (t >= off) ? ssum[t - off] : 0;
    __syncthreads();
    ssum[t] += xv;
    __syncthreads();
  }
  int excl = (t == 0) ? 0 : ssum[t - 1];
  if (2 * t < NB) lofs[2 * t] = excl;
  if (2 * t + 1 < NB) lofs[2 * t + 1] = excl + v0;
  if (t == 511) lofs[NB] = ssum[511];
  __syncthreads();

  for (int i = t; i <= NB; i += 512) ofs[c * (NB + 1) + i] = lofs[i];
  for (int i = t; i < NB; i += 512) lcnt[i] = 0;   // reuse as cursor
  __syncthreads();

#pragma unroll
  for (int u = 0; u < EPT; ++u) {
    int r = rr[u];
    if (r >= 0) {
      int e = c0 + t + u * 512;
      int b = r >> RPB_LOG;
      int rank = atomicAdd(&lcnt[b], 1);
      cv_loc[c0 + lofs[b] + rank] =
          make_int2(((r & (RPB - 1)) << 17) | cols[e], __float_as_int(vals[e]));
    }
  }
}

// ---------------------------------------------------------------------------
// Phase B: per-bucket counting sort -> 4B-packed CSR + row_ptr.
// bstart computed in-block (reduce of gcnt[0..b-1]). Coalesced strided loop
// + incremental monotone group cursor. cv_csr: (col<<15)|(bf16(val)&0x7FFF).
// ---------------------------------------------------------------------------
__global__ __launch_bounds__(256) void refine5_kernel(
    const int* __restrict__ ofs, const int* __restrict__ gcnt,
    const int2* __restrict__ cv_loc, unsigned* __restrict__ cv_csr,
    int* __restrict__ row_ptr) {
  __shared__ int gs[NCHUNK];       // group global start (edge index)
  __shared__ int q[NCHUNK + 1];    // within-bucket exclusive offsets
  __shared__ int sq[256];
  __shared__ int rcnt[RPB];
  __shared__ int rbase[RPB];
  __shared__ int bstart_s;
  const int b = blockIdx.x, t = threadIdx.x;

  // ---- bstart_b = sum_{i<b} gcnt[i] (block reduce) ----
  int part = 0;
  for (int i = t; i < b; i += 256) part += gcnt[i];
  sq[t] = part;
  __syncthreads();
  for (int off = 128; off > 0; off >>= 1) {
    if (t < off) sq[t] += sq[t + off];
    __syncthreads();
  }
  if (t == 0) bstart_s = sq[0];
  __syncthreads();

  // ---- group table + within-bucket offsets ----
  int cnt_t = 0;
  if (t < NCHUNK) {
    int g0 = ofs[t * (NB + 1) + b];
    int g1 = ofs[t * (NB + 1) + b + 1];
    gs[t] = t * CHUNK + g0;
    cnt_t = g1 - g0;
  }
  sq[t] = cnt_t;
  __syncthreads();
  for (int off = 1; off < 256; off <<= 1) {
    int v = (t >= off) ? sq[t - off] : 0;
    __syncthreads();
    sq[t] += v;
    __syncthreads();
  }
  if (t < NCHUNK) q[t] = sq[t] - cnt_t;
  if (t == 0) q[NCHUNK] = sq[255];
  if (t < RPB) rcnt[t] = 0;
  __syncthreads();
  const int Q = q[NCHUNK];

  // pass 1: row histogram; group cursor advances monotonically with i
  int lo = 0;
  for (int i = t; i < Q; i += 256) {
    while (q[lo + 1] <= i) ++lo;
    int2 e = cv_loc[gs[lo] + (i - q[lo])];
    atomicAdd(&rcnt[e.x >> 17], 1);
  }
  __syncthreads();

  int rv = (t < RPB) ? rcnt[t] : 0;
  sq[t] = rv;
  __syncthreads();
  for (int off = 1; off < RPB; off <<= 1) {
    int v = (t >= off && t < RPB) ? sq[t - off] : 0;
    __syncthreads();
    if (t < RPB) sq[t] += v;
    __syncthreads();
  }
  if (t < RPB) {
    int base = bstart_s + sq[t] - rv;
    rbase[t] = base;
    int gr = (b << RPB_LOG) + t;
    if (gr < N_NODES) row_ptr[gr] = base;
    rcnt[t] = 0;                               // reuse as cursor
  }
  if (b == 0 && t == 0) row_ptr[N_NODES] = N_EDGES;
  __syncthreads();

  // pass 2: rank-scatter, 4B pack (reads are L2-hot from pass 1)
  lo = 0;
  for (int i = t; i < Q; i += 256) {
    while (q[lo + 1] <= i) ++lo;
    int2 e = cv_loc[gs[lo] + (i - q[lo])];
    int rl = e.x >> 17;
    int rank = atomicAdd(&rcnt[rl], 1);
    float v = __int_as_float(e.y);
    unsigned vb = pk2(v, v);
    cv_csr[rbase[rl] + rank] =
        ((unsigned)(e.x & 0x1FFFF) << 15) | (vb & 0x7FFF);
  }
}

// ---------------------------------------------------------------------------
// CSR SpMM, bf16 gather table (3.2MB, L2-hot), 4B packed edges.
// 8 threads/row = 4 col-lanes x 2 edge-halves; halves combined via
// __shfl_xor(.,4). 32 rows/block -> 3125 blocks. OM: 0 bf16; 1 bf16+fp32.
// ---------------------------------------------------------------------------
template <int OM>
__global__ __launch_bounds__(256) void spmm_b16_kernel(
    const int* __restrict__ rp, const unsigned* __restrict__ colval,
    const unsigned short* __restrict__ in, unsigned short* __restrict__ outb,
    float* __restrict__ outf) {
  const int t = threadIdx.x;
  const int r = blockIdx.x * 32 + (t >> 3);   // 3125*32 == N exactly
  const int q = t & 3;
  const int hh = (t >> 2) & 1;
  const int k0 = rp[r], k1 = rp[r + 1];
  const int len0 = (k1 - k0 + 1) >> 1;
  int k = k0 + hh * len0;
  const int ke = hh ? k1 : (k0 + len0);
  float a0 = 0.f, a1 = 0.f, a2 = 0.f, a3 = 0.f;

  for (; k + 7 < ke; k += 8) {            // 8 independent gathers in flight
    unsigned cv[8];
#pragma unroll
    for (int u = 0; u < 8; ++u) cv[u] = colval[k + u];
    u16x4 g[8];
#pragma unroll
    for (int u = 0; u < 8; ++u)
      g[u] = *(const u16x4*)(in + (size_t)(cv[u] >> 15) * 16 + q * 4);
#pragma unroll
    for (int u = 0; u < 8; ++u) {
      float v = __uint_as_float((cv[u] & 0x7FFF) << 16);
      a0 += v * b2f(g[u][0]);
      a1 += v * b2f(g[u][1]);
      a2 += v * b2f(g[u][2]);
      a3 += v * b2f(g[u][3]);
    }
  }
  for (; k + 3 < ke; k += 4) {            // 4-deep tail
    unsigned cv[4];
#pragma unroll
    for (int u = 0; u < 4; ++u) cv[u] = colval[k + u];
    u16x4 g[4];
#pragma unroll
    for (int u = 0; u < 4; ++u)
      g[u] = *(const u16x4*)(in + (size_t)(cv[u] >> 15) * 16 + q * 4);
#pragma unroll
    for (int u = 0; u < 4; ++u) {
      float v = __uint_as_float((cv[u] & 0x7FFF) << 16);
      a0 += v * b2f(g[u][0]);
      a1 += v * b2f(g[u][1]);
      a2 += v * b2f(g[u][2]);
      a3 += v * b2f(g[u][3]);
    }
  }
  for (; k < ke; ++k) {
    unsigned cv = colval[k];
    u16x4 g = *(const u16x4*)(in + (size_t)(cv >> 15) * 16 + q * 4);
    float v = __uint_as_float((cv & 0x7FFF) << 16);
    a0 += v * b2f(g[0]); a1 += v * b2f(g[1]);
    a2 += v * b2f(g[2]); a3 += v * b2f(g[3]);
  }

  // combine edge halves (partner lane: same row, hh^1)
  a0 += __shfl_xor(a0, 4);
  a1 += __shfl_xor(a1, 4);
  a2 += __shfl_xor(a2, 4);
  a3 += __shfl_xor(a3, 4);

  if (hh == 0) {
    uint2 pk = make_uint2(pk2(a0, a1), pk2(a2, a3));
    *(uint2*)(outb + (size_t)r * 16 + q * 4) = pk;
    if (OM == 1)
      *(float4*)(outf + (size_t)r * 16 + q * 4) = make_float4(a0, a1, a2, a3);
  }
}

// ---------------------------------------------------------------------------
// spmm_dec: fused  t3 = A @ t2  (split gather + shfl combine -> LDS tile),
// then dec = t3 @ (W3@W4) (W34 cols built incrementally in regs, coalesced
// writes). Block = 32 rows. Reads d_ws scratch ONLY; writes dec ONLY.
// ---------------------------------------------------------------------------
__global__ __launch_bounds__(256) void spmm_dec_kernel(
    const int* __restrict__ rp, const unsigned* __restrict__ colval,
    const unsigned short* __restrict__ in, const float* __restrict__ W3,
    const float* __restrict__ W4, float* __restrict__ out) {
  __shared__ float t3s[32][20];
  const int t = threadIdx.x;
  const int r0 = blockIdx.x * 32;
  const int lr = t >> 3;
  const int q = t & 3;
  const int hh = (t >> 2) & 1;
  const int r = r0 + lr;

  // ---- W34 columns t, t+256 built incrementally ----
  float wa[16], wb[16];
#pragma unroll
  for (int kk = 0; kk < 16; ++kk) { wa[kk] = 0.f; wb[kk] = 0.f; }
#pragma unroll
  for (int m = 0; m < 32; ++m) {
    float w4A = W4[m * 512 + t];
    float w4B = W4[m * 512 + t + 256];
#pragma unroll
    for (int kk = 0; kk < 16; ++kk) {
      float w3 = W3[kk * 32 + m];         // uniform -> s_load
      wa[kk] += w3 * w4A;
      wb[kk] += w3 * w4B;
    }
  }

  // ---- split gather phase ----
  const int k0 = rp[r], k1 = rp[r + 1];
  const int len0 = (k1 - k0 + 1) >> 1;
  int k = k0 + hh * len0;
  const int ke = hh ? k1 : (k0 + len0);
  float a0 = 0.f, a1 = 0.f, a2 = 0.f, a3 = 0.f;
  for (; k + 7 < ke; k += 8) {
    unsigned cv[8];
#pragma unroll
    for (int u = 0; u < 8; ++u) cv[u] = colval[k + u];
    u16x4 g[8];
#pragma unroll
    for (int u = 0; u < 8; ++u)
      g[u] = *(const u16x4*)(in + (size_t)(cv[u] >> 15) * 16 + q * 4);
#pragma unroll
    for (int u = 0; u < 8; ++u) {
      float v = __uint_as_float((cv[u] & 0x7FFF) << 16);
      a0 += v * b2f(g[u][0]);
      a1 += v * b2f(g[u][1]);
      a2 += v * b2f(g[u][2]);
      a3 += v * b2f(g[u][3]);
    }
  }
  for (; k + 3 < ke; k += 4) {
    unsigned cv[4];
#pragma unroll
    for (int u = 0; u < 4; ++u) cv[u] = colval[k + u];
    u16x4 g[4];
#pragma unroll
    for (int u = 0; u < 4; ++u)
      g[u] = *(const u16x4*)(in + (size_t)(cv[u] >> 15) * 16 + q * 4);
#pragma unroll
    for (int u = 0; u < 4; ++u) {
      float v = __uint_as_float((cv[u] & 0x7FFF) << 16);
      a0 += v * b2f(g[u][0]);
      a1 += v * b2f(g[u][1]);
      a2 += v * b2f(g[u][2]);
      a3 += v * b2f(g[u][3]);
    }
  }
  for (; k < ke; ++k) {
    unsigned cv = colval[k];
    u16x4 g = *(const u16x4*)(in + (size_t)(cv >> 15) * 16 + q * 4);
    float v = __uint_as_float((cv & 0x7FFF) << 16);
    a0 += v * b2f(g[0]); a1 += v * b2f(g[1]);
    a2 += v * b2f(g[2]); a3 += v * b2f(g[3]);
  }
  a0 += __shfl_xor(a0, 4);
  a1 += __shfl_xor(a1, 4);
  a2 += __shfl_xor(a2, 4);
  a3 += __shfl_xor(a3, 4);
  if (hh == 0) {
    t3s[lr][q * 4 + 0] = a0;
    t3s[lr][q * 4 + 1] = a1;
    t3s[lr][q * 4 + 2] = a2;
    t3s[lr][q * 4 + 3] = a3;
  }
  __syncthreads();

  // ---- dec rows: per local row, 2 coalesced column writes/thread ----
  for (int rr = 0; rr < 32; ++rr) {
    float4 c0 = *(const float4*)&t3s[rr][0];    // uniform -> broadcast
    float4 c1 = *(const float4*)&t3s[rr][4];
    float4 c2 = *(const float4*)&t3s[rr][8];
    float4 c3 = *(const float4*)&t3s[rr][12];
    float sa = c0.x * wa[0] + c0.y * wa[1] + c0.z * wa[2] + c0.w * wa[3]
             + c1.x * wa[4] + c1.y * wa[5] + c1.z * wa[6] + c1.w * wa[7]
             + c2.x * wa[8] + c2.y * wa[9] + c2.z * wa[10] + c2.w * wa[11]
             + c3.x * wa[12] + c3.y * wa[13] + c3.z * wa[14] + c3.w * wa[15];
    float sb = c0.x * wb[0] + c0.y * wb[1] + c0.z * wb[2] + c0.w * wb[3]
             + c1.x * wb[4] + c1.y * wb[5] + c1.z * wb[6] + c1.w * wb[7]
             + c2.x * wb[8] + c2.y * wb[9] + c2.z * wb[10] + c2.w * wb[11]
             + c3.x * wb[12] + c3.y * wb[13] + c3.z * wb[14] + c3.w * wb[15];
    float* o = out + (size_t)(r0 + rr) * 512;
    o[t] = sa;
    o[t + 256] = sb;
  }
}

// ---------------------------------------------------------------------------
extern "C" void kernel_launch(void* const* d_in, const int* in_sizes, int n_in,
                              void* d_out, int out_size, void* d_ws, size_t ws_size,
                              hipStream_t stream) {
  const float* x     = (const float*)d_in[0];
  const int*   arows = (const int*)d_in[1];
  const int*   acols = (const int*)d_in[2];
  const float* avals = (const float*)d_in[3];
  const float* W1    = (const float*)d_in[4];  // [512,32]
  const float* W2    = (const float*)d_in[5];  // [32,16]
  const float* W3    = (const float*)d_in[6];  // [16,32]
  const float* W4    = (const float*)d_in[7];  // [32,512]

  float* out = (float*)d_out;
  float* dec = out;                            // [N,512] written LAST
  float* enc = out + (size_t)N_NODES * 512;    // [N,16]

  // d_ws (22.8MB <= proven 25.6MB): 3 bf16 [N,16] ping-pong buffers +
  // everything the FINAL kernel reads (cv_csr, row_ptr).
  unsigned short* bh  = (unsigned short*)d_ws;      // h; reused for t2
  unsigned short* bu  = bh + (size_t)N_NODES * 16;  // u1
  unsigned short* be  = bu + (size_t)N_NODES * 16;  // e2 bf16 copy
  unsigned* cv_csr  = (unsigned*)(be + (size_t)N_NODES * 16);  // [E] 4B packed
  int*      row_ptr = (int*)(cv_csr + N_EDGES);     // [N+1]

  // dec-region scratch — all reads complete BEFORE spmm_dec launches.
  int2*  cv_loc = (int2*)dec;                       // [E] chunk-local (8B)
  uint4* Wfrag  = (uint4*)(cv_loc + N_EDGES);       // [1024] (16B-aligned)
  int*   ofs    = (int*)(Wfrag + 1024);             // [NCHUNK][NB+1]
  int*   gcnt   = ofs + NCHUNK * (NB + 1);          // [NB]

  // ---- build CSR + pack W12 = W1@W2 fragments ----
  wconv12_kernel<<<4, 256, 0, stream>>>(W1, W2, Wfrag, gcnt);
  localsort_kernel<<<NCHUNK, 512, 0, stream>>>(arows, acols, avals, cv_loc, ofs, gcnt);
  refine5_kernel<<<NB, 256, 0, stream>>>(ofs, gcnt, cv_loc, cv_csr, row_ptr);

  // ---- pipeline (all spmms D=16, bf16 tables, 4B edges) ----
  const int spGrid = N_NODES / 32;  // 3125, exact
  mm1_kernel<<<(N_NODES + 127) / 128, 256, 0, stream>>>(x, Wfrag, bh);       // h  -> bh
  spmm_b16_kernel<0><<<spGrid, 256, 0, stream>>>(row_ptr, cv_csr, bh, bu, nullptr);   // u1 -> bu
  spmm_b16_kernel<1><<<spGrid, 256, 0, stream>>>(row_ptr, cv_csr, bu, be, enc);       // e2 -> be (+enc)
  spmm_b16_kernel<0><<<spGrid, 256, 0, stream>>>(row_ptr, cv_csr, be, bh, nullptr);   // t2 -> bh (reuse)
  spmm_dec_kernel<<<spGrid, 256, 0, stream>>>(row_ptr, cv_csr, bh, W3, W4, dec);      // t3+dec
}